// Round 4
// baseline (265.732 us; speedup 1.0000x reference)
//
#include <hip/hip_runtime.h>

// Problem dims (fixed by setup_inputs)
constexpr int Bc = 4, Cc = 128, Hc = 192, Wc = 192;
constexpr int HI = 96, WI = 96;       // half-res inputs
constexpr int NB = 64;                // n_bins
constexpr int NA = 16;                // n_att
constexpr float SCL = 95.0f / 191.0f; // align_corners scale (96->192)

typedef __attribute__((ext_vector_type(8))) short bf16x8;
typedef __attribute__((ext_vector_type(4))) float f32x4;

__device__ __forceinline__ unsigned short f2bf(float f) {
  unsigned u = __builtin_bit_cast(unsigned, f);
  unsigned r = (u + 0x7FFFu + ((u >> 16) & 1u)) >> 16;   // RNE
  return (unsigned short)r;
}
__device__ __forceinline__ float rcp_fast(float r) {
#if defined(__has_builtin)
#if __has_builtin(__builtin_amdgcn_rcpf)
  return __builtin_amdgcn_rcpf(r);
#else
  return 1.0f / r;
#endif
#else
  return 1.0f / r;
#endif
}

// ---------------------------------------------------------------------------
// Prep: pack w1 / even rows of w2 into MFMA-fragment order (bf16):
//   w1p[(nt*4+kt)*512 + l*8 + e] = w1[(nt*16 + (l&15))*128 + kt*32 + (l>>4)*8 + e]
//   w2p[kt*512 + l*8 + e]        = w2[(2*(l&15))*128   + kt*32 + (l>>4)*8 + e]
// ---------------------------------------------------------------------------
__global__ __launch_bounds__(256) void k_prep(
    const float* __restrict__ w1, const float* __restrict__ w2,
    unsigned short* __restrict__ w1p, unsigned short* __restrict__ w2p)
{
  const int t = blockIdx.x * 256 + threadIdx.x;   // 0..18431
  if (t < 16384) {
    const int e  = t & 7;
    const int l  = (t >> 3) & 63;
    const int kt = (t >> 9) & 3;
    const int nt = t >> 11;
    const int n  = nt * 16 + (l & 15);
    const int k  = kt * 32 + (l >> 4) * 8 + e;
    w1p[t] = f2bf(w1[n * 128 + k]);
  } else {
    const int u  = t - 16384;                     // 0..2047
    const int e  = u & 7;
    const int l  = (u >> 3) & 63;
    const int kt = u >> 9;
    const int n  = 2 * (l & 15);                  // even rows only
    const int k  = kt * 32 + (l >> 4) * 8 + e;
    w2p[u] = f2bf(w2[n * 128 + k]);
  }
}

// ---------------------------------------------------------------------------
// R4: FUSED row kernel. Block = one image row (b,y); 384 threads = 6 waves.
// Rationale: R3 showed per-kernel sums (~105us) << wall (213us) -> the
// 3-dispatch structure (launch/dependency boundaries + 9.4MB att round-trip)
// is the bottleneck. Fuse: phase A = k_att for all 192 px -> att in LDS;
// phase B = k_bins reading att from LDS. ws shrinks to 36KB (w1p/w2p only).
//
// LDS choreography (peak 81920 B = exactly 2 blocks/CU):
//   [0      ..32768) w1_s  (frag-linear bf16)         phase A GEMM1
//   [32768  ..81920) row_s [128][96] f32, XOR-swizzled phase A interp
//     after af-build barrier, row_s region re-used as:
//   [32768  ..58880) a1_s  per-wave [16][136] bf16    GEMM1->GEMM2 transpose
//   [58880  ..74240) att_s [192][20] f32              phase A out / B in
//   phase B: [0..24576) pbrow [64][96] f32 ; [24576..49152) xch [32][192]
//
// row_s swizzle: word = c*96 + (xi ^ (qd<<3)) where qd=(c>>3)&3 — pitch 96
// is 32-bank-aligned, so the 4 qd-groups (same xi, different c) would hit
// the same bank 4-way; XOR by qd*8 spreads them. Bijective within [0,96).
// ---------------------------------------------------------------------------
__global__ __launch_bounds__(384, 3) void k_row(
    const float* __restrict__ x, const float* __restrict__ pbe,
    const unsigned short* __restrict__ w1p, const float* __restrict__ b1,
    const unsigned short* __restrict__ w2p, const float* __restrict__ b2,
    const float* __restrict__ pb,
    float* __restrict__ out0, float* __restrict__ out1)
{
  __shared__ __align__(16) unsigned char smem[81920];
  unsigned short* w1_s  = (unsigned short*)smem;            // [0..32768)
  float*          row_s = (float*)(smem + 32768);           // [128][96] swz
  unsigned short* a1_b  = (unsigned short*)(smem + 32768);  // per-wave slots
  float*          att_s = (float*)(smem + 58880);           // [192][20]
  float*          pbrow = (float*)smem;                     // [64][96] (B)
  float*          xch   = (float*)(smem + 24576);           // [32][192] (B)

  const int tid = threadIdx.x;      // 0..383
  const int y = blockIdx.x;
  const int b = blockIdx.y;

  const int lane = tid & 63;
  const int wv = tid >> 6;          // wave 0..5
  const int ln = lane & 15;
  const int qd = lane >> 4;

  const float ysf = y * SCL;
  const int y0 = (int)ysf;
  const int y1 = min(y0 + 1, HI - 1);
  const float wy = ysf - (float)y0;

  // ================= PHASE A: att for all 192 px of row (b,y) =============

  // ---- w1p stage loads (global->reg), issued first: 6 x float4 (guarded)
  float4 wstage[6];
  {
    const float4* wp4 = (const float4*)w1p;   // 2048 float4
    #pragma unroll
    for (int i = 0; i < 6; ++i) {
      const int u = tid + 384 * i;
      wstage[i] = (u < 2048) ? wp4[u] : float4{0.f, 0.f, 0.f, 0.f};
    }
  }

  // ---- hoisted w2 fragments + biases
  bf16x8 b2f[4];
  #pragma unroll
  for (int kt = 0; kt < 4; ++kt)
    b2f[kt] = *(const bf16x8*)&w2p[kt * 512 + lane * 8];
  float bias1[8];
  #pragma unroll
  for (int nt = 0; nt < 8; ++nt) bias1[nt] = b1[nt * 16 + ln];
  const float bias2 = b2[2 * ln];

  // ---- hoisted x loads for both m-tiles: xr[mt][kt*8+j]
  float xr[2][32];
  #pragma unroll
  for (int mt = 0; mt < 2; ++mt) {
    const int px = wv * 32 + mt * 16 + ln;
    #pragma unroll
    for (int kt = 0; kt < 4; ++kt) {
      #pragma unroll
      for (int j = 0; j < 8; ++j) {
        const int c = kt * 32 + qd * 8 + j;
        xr[mt][kt * 8 + j] = x[((size_t)(b * Cc + c) * Hc + y) * Wc + px];
      }
    }
  }

  // ---- stage row_s: y-interp of pbe, full row, XOR-swizzled layout
  #pragma unroll
  for (int i = 0; i < 32; ++i) {
    const int f = tid + 384 * i;        // 0..12287
    const int c = f / 96;
    const int xi = f - c * 96;
    const float* p = pbe + (size_t)(b * Cc + c) * (HI * WI);
    const float top = p[y0 * WI + xi];
    const float bot = p[y1 * WI + xi];
    row_s[c * 96 + (xi ^ ((((c >> 3) & 3)) << 3))] = top + wy * (bot - top);
  }

  // ---- w1 stage: reg -> LDS (linear, conflict-free)
  {
    float4* ws4 = (float4*)w1_s;
    #pragma unroll
    for (int i = 0; i < 6; ++i) {
      const int u = tid + 384 * i;
      if (u < 2048) ws4[u] = wstage[i];
    }
  }
  __syncthreads();   // B1: row_s + w1_s ready

  // ---- build A-fragments for both m-tiles (consumes row_s)
  bf16x8 af[2][4];
  const int sw = qd << 3;             // row_s swizzle key for this lane's c's
  #pragma unroll
  for (int mt = 0; mt < 2; ++mt) {
    const int px = wv * 32 + mt * 16 + ln;
    const float xsf = (float)px * SCL;
    const int xl = (int)xsf;          // 0..94
    const float wx = xsf - (float)xl;
    const int i0 = xl ^ sw;
    const int i1 = (xl + 1) ^ sw;
    #pragma unroll
    for (int kt = 0; kt < 4; ++kt) {
      #pragma unroll
      for (int j = 0; j < 8; ++j) {
        const int c = kt * 32 + qd * 8 + j;
        const float v0 = row_s[c * 96 + i0];
        const float v1 = row_s[c * 96 + i1];
        af[mt][kt][j] = (short)f2bf(xr[mt][kt * 8 + j] + v0 + wx * (v1 - v0));
      }
    }
  }
  __syncthreads();   // B2: row_s dead everywhere -> a1_b/att_s regions safe

  // ---- per-wave a1 scratch slot [16][136] bf16
  unsigned short* a1w = a1_b + wv * (16 * 136);

  #pragma unroll
  for (int mt = 0; mt < 2; ++mt) {
    // GEMM1: C[16m][128n] for this wave's m-tile (B from LDS, frag-linear)
    f32x4 acc[8];
    #pragma unroll
    for (int nt = 0; nt < 8; ++nt) acc[nt] = f32x4{0.f, 0.f, 0.f, 0.f};
    #pragma unroll
    for (int nt = 0; nt < 8; ++nt) {
      #pragma unroll
      for (int kt = 0; kt < 4; ++kt) {
        const bf16x8 bf = *(const bf16x8*)&w1_s[(nt * 4 + kt) * 512 + lane * 8];
        acc[nt] = __builtin_amdgcn_mfma_f32_16x16x32_bf16(af[mt][kt], bf, acc[nt], 0, 0, 0);
      }
    }
    // epilogue: relu(+bias) -> a1w (wave-private; DS in-order per wave)
    #pragma unroll
    for (int nt = 0; nt < 8; ++nt) {
      const int n = nt * 16 + ln;
      const float bias = bias1[nt];
      #pragma unroll
      for (int r = 0; r < 4; ++r) {
        a1w[(qd * 4 + r) * 136 + n] = f2bf(fmaxf(acc[nt][r] + bias, 0.f));
      }
    }
    // GEMM2: att[16m][16j]
    f32x4 acc2 = f32x4{0.f, 0.f, 0.f, 0.f};
    #pragma unroll
    for (int kt = 0; kt < 4; ++kt) {
      const bf16x8 a2 = *(const bf16x8*)&a1w[ln * 136 + kt * 32 + qd * 8];
      acc2 = __builtin_amdgcn_mfma_f32_16x16x32_bf16(a2, b2f[kt], acc2, 0, 0, 0);
    }
    #pragma unroll
    for (int r = 0; r < 4; ++r) {
      const int opx = wv * 32 + mt * 16 + qd * 4 + r;
      att_s[opx * 20 + ln] = fmaxf(acc2[r] + bias2, 0.f) + 0.001f;
    }
  }
  __syncthreads();   // B3: att_s complete; w1_s/a1_b dead

  // ================= PHASE B: bins + sort (att from LDS) ==================

  const int h = (tid >= 192) ? 1 : 0;   // bin half (wave-uniform)
  const int px = tid - 192 * h;         // pixel 0..191

  // att for this pixel: 16 floats from att_s (16B-aligned, pitch 20)
  float am[16];
  {
    const f32x4* ap = (const f32x4*)&att_s[px * 20];
    const f32x4 a0 = ap[0], a1 = ap[1], a2 = ap[2], a3 = ap[3];
    am[0] = a0[0];  am[1] = a0[1];  am[2] = a0[2];  am[3] = a0[3];
    am[4] = a1[0];  am[5] = a1[1];  am[6] = a1[2];  am[7] = a1[3];
    am[8] = a2[0];  am[9] = a2[1];  am[10] = a2[2]; am[11] = a2[3];
    am[12] = a3[0]; am[13] = a3[1]; am[14] = a3[2]; am[15] = a3[3];
  }

  // ---- stage y-interpolated pb rows for all 64 bins: 1536 float4 positions
  #pragma unroll
  for (int i = 0; i < 4; ++i) {
    const int u = tid + 384 * i;          // 0..1535
    const int k = u / 24;
    const int g = u - k * 24;             // float4 group in row
    const float* base = pb + (size_t)(b * NB + k) * (HI * WI);
    const float4 t4 = *(const float4*)&base[y0 * WI + g * 4];
    const float4 b4 = *(const float4*)&base[y1 * WI + g * 4];
    float4 r;
    r.x = t4.x + wy * (b4.x - t4.x);
    r.y = t4.y + wy * (b4.y - t4.y);
    r.z = t4.z + wy * (b4.z - t4.z);
    r.w = t4.w + wy * (b4.w - t4.w);
    *(float4*)&pbrow[k * 96 + g * 4] = r;
  }
  __syncthreads();   // B4: pbrow ready

  const float xsf = px * SCL;
  const int x0 = (int)xsf;          // <= 94
  const float wx = xsf - (float)x0;

  const size_t obase = (size_t)(b * NB) * (Hc * Wc) + (size_t)y * Wc + px;
  float v[32];                      // this thread's 32 bins (k = h*32 + i)

  // ---- delta: 4 bins in flight -> 4 independent rcp chains
  #pragma unroll
  for (int kb = 0; kb < 32; kb += 4) {
    float bc[4], dl[4];
    #pragma unroll
    for (int q = 0; q < 4; ++q) {
      const int k = h * 32 + kb + q;
      const float v0 = pbrow[k * 96 + x0], v1 = pbrow[k * 96 + x0 + 1];
      bc[q] = v0 + wx * (v1 - v0);
      dl[q] = 0.f;
    }
    #pragma unroll
    for (int j = 0; j < NA; ++j) {
      const float a = am[j];
      #pragma unroll
      for (int q = 0; q < 4; ++q) {
        const float d = a - bc[q];
        const float rq = fmaf(300.f * d, d, 1.f);
        dl[q] = fmaf(d, rcp_fast(rq), dl[q]);
      }
    }
    #pragma unroll
    for (int q = 0; q < 4; ++q) {
      const float bnc = fmaf(dl[q], 1.f / 16.f, bc[q]);
      out0[obase + (size_t)(h * 32 + kb + q) * (Hc * Wc)] = bnc;
      v[kb + q] = fmaf(9.999f, bnc, 0.001f);
    }
  }

  // ---- per-thread bitonic sort of 32: h0 ascending, h1 descending
  if (h == 0) {
    #pragma unroll
    for (int size = 2; size <= 32; size <<= 1)
      #pragma unroll
      for (int stride = size >> 1; stride >= 1; stride >>= 1)
        #pragma unroll
        for (int i = 0; i < 32; ++i)
          if ((i & stride) == 0) {
            const int j = i | stride;
            const bool asc = ((i & size) == 0);
            const float a = v[i], c = v[j];
            const float lo = fminf(a, c), hi = fmaxf(a, c);
            v[i] = asc ? lo : hi;
            v[j] = asc ? hi : lo;
          }
  } else {
    #pragma unroll
    for (int size = 2; size <= 32; size <<= 1)
      #pragma unroll
      for (int stride = size >> 1; stride >= 1; stride >>= 1)
        #pragma unroll
        for (int i = 0; i < 32; ++i)
          if ((i & stride) == 0) {
            const int j = i | stride;
            const bool asc = ((i & size) != 0);   // descending overall
            const float a = v[i], c = v[j];
            const float lo = fminf(a, c), hi = fmaxf(a, c);
            v[i] = asc ? lo : hi;
            v[j] = asc ? hi : lo;
          }
  }

  // ---- cross-thread stride-32 CE layer through LDS xch (disjoint region)
  __syncthreads();                       // all pbrow reads done
  if (h) {
    #pragma unroll
    for (int i = 0; i < 32; ++i) xch[i * 192 + px] = v[i];
  }
  __syncthreads();
  if (!h) {
    #pragma unroll
    for (int i = 0; i < 32; ++i) {
      const float o = xch[i * 192 + px];
      const float mn = fminf(v[i], o), mx = fmaxf(v[i], o);
      v[i] = mn;
      xch[i * 192 + px] = mx;
    }
  }
  __syncthreads();
  if (h) {
    #pragma unroll
    for (int i = 0; i < 32; ++i) v[i] = xch[i * 192 + px];
  }

  // ---- each half is bitonic; 5 ascending merge layers finish the sort
  #pragma unroll
  for (int stride = 16; stride >= 1; stride >>= 1)
    #pragma unroll
    for (int i = 0; i < 32; ++i)
      if ((i & stride) == 0) {
        const int j = i | stride;
        const float a = v[i], c = v[j];
        v[i] = fminf(a, c);
        v[j] = fmaxf(a, c);
      }

  // h0 holds global ranks 0..31, h1 ranks 32..63
  #pragma unroll
  for (int i = 0; i < 32; ++i) {
    out1[obase + (size_t)(h * 32 + i) * (Hc * Wc)] =
        fminf(fmaxf(v[i], 0.001f), 10.0f);
  }
}

// ---------------------------------------------------------------------------
extern "C" void kernel_launch(void* const* d_in, const int* in_sizes, int n_in,
                              void* d_out, int out_size, void* d_ws, size_t ws_size,
                              hipStream_t stream) {
  const float* x   = (const float*)d_in[0];   // (4,128,192,192)
  const float* pb  = (const float*)d_in[1];   // (4,64,96,96)
  const float* pbe = (const float*)d_in[2];   // (4,128,96,96)
  const float* w1  = (const float*)d_in[3];   // (128,128)
  const float* b1  = (const float*)d_in[4];   // (128,)
  const float* w2  = (const float*)d_in[5];   // (32,128)
  const float* b2  = (const float*)d_in[6];   // (32,)

  float* out0 = (float*)d_out;                       // bin_new_centers
  float* out1 = out0 + (size_t)Bc * NB * Hc * Wc;    // bin_centers

  // ws layout: [w1p 32KB][w2p 4KB] — att workspace eliminated (fused)
  unsigned short* w1p = (unsigned short*)d_ws;
  unsigned short* w2p = w1p + 16384;

  k_prep<<<72, 256, 0, stream>>>(w1, w2, w1p, w2p);

  dim3 g(Hc, Bc);
  k_row<<<g, 384, 0, stream>>>(x, pbe, w1p, b1, w2p, b2, pb, out0, out1);
}

// Round 5
// 235.639 us; speedup vs baseline: 1.1277x; 1.1277x over previous
//
#include <hip/hip_runtime.h>

// Problem dims (fixed by setup_inputs)
constexpr int Bc = 4, Cc = 128, Hc = 192, Wc = 192;
constexpr int HI = 96, WI = 96;       // half-res inputs
constexpr int NB = 64;                // n_bins
constexpr int NA = 16;                // n_att
constexpr float SCL = 95.0f / 191.0f; // align_corners scale (96->192)

typedef __attribute__((ext_vector_type(8))) short bf16x8;
typedef __attribute__((ext_vector_type(4))) float f32x4;

__device__ __forceinline__ unsigned short f2bf(float f) {
  unsigned u = __builtin_bit_cast(unsigned, f);
  unsigned r = (u + 0x7FFFu + ((u >> 16) & 1u)) >> 16;   // RNE
  return (unsigned short)r;
}
__device__ __forceinline__ float rcp_fast(float r) {
#if defined(__has_builtin)
#if __has_builtin(__builtin_amdgcn_rcpf)
  return __builtin_amdgcn_rcpf(r);
#else
  return 1.0f / r;
#endif
#else
  return 1.0f / r;
#endif
}

// ---------------------------------------------------------------------------
// Prep: pack w1 / even rows of w2 into MFMA-fragment order (bf16):
//   w1p[(nt*4+kt)*512 + l*8 + e] = w1[(nt*16 + (l&15))*128 + kt*32 + (l>>4)*8 + e]
//   w2p[kt*512 + l*8 + e]        = w2[(2*(l&15))*128   + kt*32 + (l>>4)*8 + e]
// nt<4 fragments occupy the first 16KB, nt>=4 the second 16KB (half-split).
// ---------------------------------------------------------------------------
__global__ __launch_bounds__(256) void k_prep(
    const float* __restrict__ w1, const float* __restrict__ w2,
    unsigned short* __restrict__ w1p, unsigned short* __restrict__ w2p)
{
  const int t = blockIdx.x * 256 + threadIdx.x;   // 0..18431
  if (t < 16384) {
    const int e  = t & 7;
    const int l  = (t >> 3) & 63;
    const int kt = (t >> 9) & 3;
    const int nt = t >> 11;
    const int n  = nt * 16 + (l & 15);
    const int k  = kt * 32 + (l >> 4) * 8 + e;
    w1p[t] = f2bf(w1[n * 128 + k]);
  } else {
    const int u  = t - 16384;                     // 0..2047
    const int e  = u & 7;
    const int l  = (u >> 3) & 63;
    const int kt = u >> 9;
    const int n  = 2 * (l & 15);                  // even rows only
    const int k  = kt * 32 + (l >> 4) * 8 + e;
    w2p[u] = f2bf(w2[n * 128 + k]);
  }
}

// ---------------------------------------------------------------------------
// K1 (MFMA). One block per (b, y, 64-px x-tile). 256 threads = 4 waves.
// R5: two-pass w1 (16KB LDS half, GEMM1 nt0-3 then nt4-7) -> LDS 35328 B
// -> 4 blocks/CU (was 3 at 51.7KB). Second half staged global->reg early
// (issue after B2, hidden under pass-1 MFMAs), reg->LDS after B3 barrier.
// R4 lesson: 81920B LDS = exactly half the pool -> 1 block/CU; never size
// LDS to the boundary. R1 lesson: don't crush VGPRs below ~110.
// ---------------------------------------------------------------------------
__global__ __launch_bounds__(256, 4) void k_att(
    const float* __restrict__ x, const float* __restrict__ pbe,
    const unsigned short* __restrict__ w1p, const float* __restrict__ b1,
    const unsigned short* __restrict__ w2p, const float* __restrict__ b2,
    float* __restrict__ att)
{
  constexpr int PH = 136;   // a1_s pitch (bf16)
  constexpr int RP = 37;    // row_s pitch (f32), odd
  // [w1_s half 16384B][row_s(=a1_s alias) 18944B] = 35328 B
  __shared__ __align__(16) unsigned char smem[16384 + 128 * RP * 4];
  unsigned short* w1_s  = (unsigned short*)smem;                // 8192 shorts
  float*          row_s = (float*)(smem + 16384);               // [128][37]
  unsigned short* a1_s  = (unsigned short*)(smem + 16384);      // [64][136]

  const int tid = threadIdx.x;
  const int xg0 = blockIdx.x * 64;
  const int y = blockIdx.y;
  const int b = blockIdx.z;

  const float ysf = y * SCL;
  const int y0 = (int)ysf;
  const int y1 = min(y0 + 1, HI - 1);
  const float wy = ysf - (float)y0;
  const int xi0 = (int)(xg0 * SCL);

  const int lane = tid & 63;
  const int wv = tid >> 6;        // wave id 0..3
  const int ln = lane & 15;
  const int qd = lane >> 4;
  const int m0 = wv * 16;

  const int xg = xg0 + m0 + ln;
  const float xsf = (float)xg * SCL;
  const int x0i = (int)xsf;
  const float wx = xsf - (float)x0i;
  const int xl = x0i - xi0;             // 0..32, xl+1 <= 33

  // ---- w1 half-0 stage loads (global->reg), issued first: 4 x float4
  float4 wstageA[4];
  {
    const float4* wp4 = (const float4*)w1p;   // half0 = first 1024 float4
    #pragma unroll
    for (int i = 0; i < 4; ++i) wstageA[i] = wp4[tid + 256 * i];
  }

  // ---- hoisted x loads: xr[kt*8+j] = x[c = kt*32+qd*8+j][y][xg]
  float xr[32];
  #pragma unroll
  for (int kt = 0; kt < 4; ++kt) {
    #pragma unroll
    for (int j = 0; j < 8; ++j) {
      const int c = kt * 32 + qd * 8 + j;
      xr[kt * 8 + j] = x[((size_t)(b * Cc + c) * Hc + y) * Wc + xg];
    }
  }

  // ---- phase 1: row_s[c][xi] = y-interp of pbe (coalesced loads, f32)
  #pragma unroll
  for (int i = 0; i < 18; ++i) {
    const int f = tid + 256 * i;        // 0..4607
    const int c = f / 36;
    const int xi = f - c * 36;
    const int xgl = min(xi0 + xi, WI - 1);
    const float* p = pbe + (size_t)(b * Cc + c) * (HI * WI);
    const float top = p[y0 * WI + xgl];
    const float bot = p[y1 * WI + xgl];
    row_s[c * RP + xi] = top + wy * (bot - top);
  }

  // ---- w1 half-0: reg -> LDS (linear, conflict-free)
  {
    float4* ws4 = (float4*)w1_s;
    #pragma unroll
    for (int i = 0; i < 4; ++i) ws4[tid + 256 * i] = wstageA[i];
  }
  __syncthreads();   // B1: row_s + w1_s(half0) ready

  // ---- build A-fragments in registers from xr + row_s
  bf16x8 af[4];
  #pragma unroll
  for (int kt = 0; kt < 4; ++kt) {
    #pragma unroll
    for (int j = 0; j < 8; ++j) {
      const int c = kt * 32 + qd * 8 + j;
      const float v0 = row_s[c * RP + xl];
      const float v1 = row_s[c * RP + xl + 1];
      af[kt][j] = (short)f2bf(xr[kt * 8 + j] + v0 + wx * (v1 - v0));
    }
  }
  __syncthreads();   // B2: row_s dead -> region reusable as a1_s

  // ---- issue w1 half-1 loads now (consumed after B3; hidden under pass-1)
  float4 wstageB[4];
  {
    const float4* wp4 = (const float4*)w1p;
    #pragma unroll
    for (int i = 0; i < 4; ++i) wstageB[i] = wp4[1024 + tid + 256 * i];
  }
  float bias1[8];
  #pragma unroll
  for (int nt = 0; nt < 8; ++nt) bias1[nt] = b1[nt * 16 + ln];

  // ---- GEMM1 pass 1: nt = 0..3 (B from LDS half0, frag-linear)
  f32x4 acc[8];
  #pragma unroll
  for (int nt = 0; nt < 8; ++nt) acc[nt] = f32x4{0.f, 0.f, 0.f, 0.f};
  #pragma unroll
  for (int nt = 0; nt < 4; ++nt) {
    #pragma unroll
    for (int kt = 0; kt < 4; ++kt) {
      const bf16x8 bf = *(const bf16x8*)&w1_s[(nt * 4 + kt) * 512 + lane * 8];
      acc[nt] = __builtin_amdgcn_mfma_f32_16x16x32_bf16(af[kt], bf, acc[nt], 0, 0, 0);
    }
  }
  // epilogue pass 1: relu(+bias) -> a1_s n=0..63 (wave-private rows)
  #pragma unroll
  for (int nt = 0; nt < 4; ++nt) {
    const int n = nt * 16 + ln;
    const float bias = bias1[nt];
    #pragma unroll
    for (int r = 0; r < 4; ++r) {
      const int m = m0 + qd * 4 + r;
      a1_s[m * PH + n] = f2bf(fmaxf(acc[nt][r] + bias, 0.f));
    }
  }
  __syncthreads();   // B3: all waves done reading w1 half0

  // ---- w1 half-1: reg -> LDS; w2 fragments issued alongside
  {
    float4* ws4 = (float4*)w1_s;
    #pragma unroll
    for (int i = 0; i < 4; ++i) ws4[tid + 256 * i] = wstageB[i];
  }
  bf16x8 b2f[4];
  #pragma unroll
  for (int kt = 0; kt < 4; ++kt)
    b2f[kt] = *(const bf16x8*)&w2p[kt * 512 + lane * 8];
  const float bias2 = b2[2 * ln];
  __syncthreads();   // B4: w1 half1 ready

  // ---- GEMM1 pass 2: nt = 4..7
  #pragma unroll
  for (int nt = 4; nt < 8; ++nt) {
    #pragma unroll
    for (int kt = 0; kt < 4; ++kt) {
      const bf16x8 bf = *(const bf16x8*)&w1_s[((nt - 4) * 4 + kt) * 512 + lane * 8];
      acc[nt] = __builtin_amdgcn_mfma_f32_16x16x32_bf16(af[kt], bf, acc[nt], 0, 0, 0);
    }
  }
  #pragma unroll
  for (int nt = 4; nt < 8; ++nt) {
    const int n = nt * 16 + ln;
    const float bias = bias1[nt];
    #pragma unroll
    for (int r = 0; r < 4; ++r) {
      const int m = m0 + qd * 4 + r;
      a1_s[m * PH + n] = f2bf(fmaxf(acc[nt][r] + bias, 0.f));
    }
  }
  // no __syncthreads: each wave reads back only rows it wrote (DS in-order/wave)

  // ---- GEMM2: att[64m][16j] = a1[64m][128k] * w2e[16j][128k]^T
  f32x4 acc2 = f32x4{0.f, 0.f, 0.f, 0.f};
  #pragma unroll
  for (int kt = 0; kt < 4; ++kt) {
    const bf16x8 a2 = *(const bf16x8*)&a1_s[(m0 + ln) * PH + kt * 32 + qd * 8];
    acc2 = __builtin_amdgcn_mfma_f32_16x16x32_bf16(a2, b2f[kt], acc2, 0, 0, 0);
  }
  #pragma unroll
  for (int r = 0; r < 4; ++r) {
    const int opx = m0 + qd * 4 + r;
    const float v = fmaxf(acc2[r] + bias2, 0.f) + 0.001f;
    att[((size_t)((b * Hc + y) * Wc) + xg0 + opx) * NA + ln] = v;
  }
}

// ---------------------------------------------------------------------------
// K2: block = half an image row (96 px), 192 threads = 96 px x 2 bin-halves.
// R5: old grid (768 blocks) = only 3 blocks/CU of total work -> Occ 24%.
// Split rows in half: grid 1536, LDS 13056B, bounds(192,6) -> ~8 blocks/CU
// schedulable. Sort-direction divergence (h splits wave 1) removed by
// folding polarity into the CE flag: asc = ((i&size)==0) != h. Edge px=191
// now stages a clamped duplicate (exact reference semantics).
// ---------------------------------------------------------------------------
__global__ __launch_bounds__(192, 6) void k_bins(
    const float* __restrict__ pb, const float* __restrict__ att,
    float* __restrict__ out0, float* __restrict__ out1)
{
  constexpr int PW = 51;                      // pbrow pitch (odd)
  __shared__ __align__(16) float smem2[NB * PW];   // 13056 B
  float* pbrow = smem2;                       // [64][51], 50 used
  float* xch   = smem2;                       // [32][96] alias after delta

  const int tid = threadIdx.x;      // 0..191
  const int y  = blockIdx.x;
  const int b  = blockIdx.y;
  const int hx = blockIdx.z;        // x-half 0/1

  const int h  = (tid >= 96) ? 1 : 0;   // bin half
  const int p  = tid - 96 * h;          // local pixel 0..95
  const int px = 96 * hx + p;           // global pixel

  const float ysf = y * SCL;
  const int y0 = (int)ysf;
  const int y1 = min(y0 + 1, HI - 1);
  const float wy = ysf - (float)y0;

  const int xi0 = hx ? 47 : 0;          // window start: (int)(96*SCL) = 47

  // att for this pixel: 16 floats, contiguous — issue first (independent)
  float am[16];
  {
    const float4* ap = (const float4*)(att + ((size_t)((b * Hc + y) * Wc) + px) * NA);
    const float4 a0 = ap[0], a1 = ap[1], a2 = ap[2], a3 = ap[3];
    am[0] = a0.x;  am[1] = a0.y;  am[2] = a0.z;  am[3] = a0.w;
    am[4] = a1.x;  am[5] = a1.y;  am[6] = a1.z;  am[7] = a1.w;
    am[8] = a2.x;  am[9] = a2.y;  am[10] = a2.z; am[11] = a2.w;
    am[12] = a3.x; am[13] = a3.y; am[14] = a3.z; am[15] = a3.w;
  }

  // ---- stage y-interpolated pb window [64 bins][50 xi] (clamped)
  #pragma unroll
  for (int i = 0; i < 17; ++i) {
    const int u = tid + 192 * i;          // 0..3263
    if (u < 3200) {
      const int k = u / 50;
      const int xi = u - k * 50;
      const int xs = min(xi0 + xi, WI - 1);
      const float* base = pb + (size_t)(b * NB + k) * (HI * WI);
      const float top = base[y0 * WI + xs];
      const float bot = base[y1 * WI + xs];
      pbrow[k * PW + xi] = top + wy * (bot - top);
    }
  }
  __syncthreads();

  const float xsf = px * SCL;
  const int x0 = (int)xsf;
  const float wx = xsf - (float)x0;
  const int xl = x0 - xi0;              // 0..48, xl+1 <= 49

  const size_t obase = (size_t)(b * NB) * (Hc * Wc) + (size_t)y * Wc + px;
  float v[32];                          // this thread's 32 bins (k = h*32 + i)

  // ---- delta: 4 bins in flight -> 4 independent rcp chains
  #pragma unroll
  for (int kb = 0; kb < 32; kb += 4) {
    float bc[4], dl[4];
    #pragma unroll
    for (int q = 0; q < 4; ++q) {
      const int k = h * 32 + kb + q;
      const float v0 = pbrow[k * PW + xl], v1 = pbrow[k * PW + xl + 1];
      bc[q] = v0 + wx * (v1 - v0);
      dl[q] = 0.f;
    }
    #pragma unroll
    for (int j = 0; j < NA; ++j) {
      const float a = am[j];
      #pragma unroll
      for (int q = 0; q < 4; ++q) {
        const float d = a - bc[q];
        const float rq = fmaf(300.f * d, d, 1.f);
        dl[q] = fmaf(d, rcp_fast(rq), dl[q]);
      }
    }
    #pragma unroll
    for (int q = 0; q < 4; ++q) {
      const float bnc = fmaf(dl[q], 1.f / 16.f, bc[q]);
      out0[obase + (size_t)(h * 32 + kb + q) * (Hc * Wc)] = bnc;
      v[kb + q] = fmaf(9.999f, bnc, 0.001f);
    }
  }

  // ---- per-thread bitonic sort of 32: h0 ascending, h1 descending.
  // Polarity folded into the flag -> single network, no divergent branch.
  #pragma unroll
  for (int size = 2; size <= 32; size <<= 1) {
    #pragma unroll
    for (int stride = size >> 1; stride >= 1; stride >>= 1) {
      #pragma unroll
      for (int i = 0; i < 32; ++i) {
        if ((i & stride) == 0) {
          const int j = i | stride;
          const bool asc = (((i & size) == 0) != (h == 1));
          const float a = v[i], c = v[j];
          const float lo = fminf(a, c), hi = fmaxf(a, c);
          v[i] = asc ? lo : hi;
          v[j] = asc ? hi : lo;
        }
      }
    }
  }

  // ---- cross-thread stride-32 CE layer through LDS (pbrow dead)
  __syncthreads();                       // all pbrow reads done
  if (h) {
    #pragma unroll
    for (int i = 0; i < 32; ++i) xch[i * 96 + p] = v[i];
  }
  __syncthreads();
  if (!h) {
    #pragma unroll
    for (int i = 0; i < 32; ++i) {
      const float o = xch[i * 96 + p];
      const float mn = fminf(v[i], o), mx = fmaxf(v[i], o);
      v[i] = mn;
      xch[i * 96 + p] = mx;
    }
  }
  __syncthreads();
  if (h) {
    #pragma unroll
    for (int i = 0; i < 32; ++i) v[i] = xch[i * 96 + p];
  }

  // ---- each half is bitonic; 5 ascending merge layers finish the sort
  #pragma unroll
  for (int stride = 16; stride >= 1; stride >>= 1) {
    #pragma unroll
    for (int i = 0; i < 32; ++i) {
      if ((i & stride) == 0) {
        const int j = i | stride;
        const float a = v[i], c = v[j];
        v[i] = fminf(a, c);
        v[j] = fmaxf(a, c);
      }
    }
  }

  // h0 holds global ranks 0..31, h1 ranks 32..63
  #pragma unroll
  for (int i = 0; i < 32; ++i) {
    out1[obase + (size_t)(h * 32 + i) * (Hc * Wc)] =
        fminf(fmaxf(v[i], 0.001f), 10.0f);
  }
}

// ---------------------------------------------------------------------------
extern "C" void kernel_launch(void* const* d_in, const int* in_sizes, int n_in,
                              void* d_out, int out_size, void* d_ws, size_t ws_size,
                              hipStream_t stream) {
  const float* x   = (const float*)d_in[0];   // (4,128,192,192)
  const float* pb  = (const float*)d_in[1];   // (4,64,96,96)
  const float* pbe = (const float*)d_in[2];   // (4,128,96,96)
  const float* w1  = (const float*)d_in[3];   // (128,128)
  const float* b1  = (const float*)d_in[4];   // (128,)
  const float* w2  = (const float*)d_in[5];   // (32,128)
  const float* b2  = (const float*)d_in[6];   // (32,)

  float* out0 = (float*)d_out;                       // bin_new_centers
  float* out1 = out0 + (size_t)Bc * NB * Hc * Wc;    // bin_centers

  // ws layout: [w1p 32KB][w2p 4KB][pad to 64KB][att f32 9.4MB]
  unsigned short* w1p = (unsigned short*)d_ws;
  unsigned short* w2p = w1p + 16384;
  float* att = (float*)((char*)d_ws + 65536);        // [b][y][x][j]

  k_prep<<<72, 256, 0, stream>>>(w1, w2, w1p, w2p);

  dim3 g1(Wc / 64, Hc, Bc);
  k_att<<<g1, 256, 0, stream>>>(x, pbe, w1p, b1, w2p, b2, att);

  dim3 g2(Hc, Bc, 2);
  k_bins<<<g2, 192, 0, stream>>>(pb, att, out0, out1);
}

// Round 7
// 215.058 us; speedup vs baseline: 1.2356x; 1.0957x over previous
//
#include <hip/hip_runtime.h>

// Problem dims (fixed by setup_inputs)
constexpr int Bc = 4, Cc = 128, Hc = 192, Wc = 192;
constexpr int HI = 96, WI = 96;       // half-res inputs
constexpr int NB = 64;                // n_bins
constexpr int NA = 16;                // n_att
constexpr float SCL = 95.0f / 191.0f; // align_corners scale (96->192)

typedef __attribute__((ext_vector_type(8))) short bf16x8;
typedef __attribute__((ext_vector_type(4))) float f32x4;

__device__ __forceinline__ unsigned short f2bf(float f) {
  unsigned u = __builtin_bit_cast(unsigned, f);
  unsigned r = (u + 0x7FFFu + ((u >> 16) & 1u)) >> 16;   // RNE
  return (unsigned short)r;
}
__device__ __forceinline__ float rcp_fast(float r) {
#if defined(__has_builtin)
#if __has_builtin(__builtin_amdgcn_rcpf)
  return __builtin_amdgcn_rcpf(r);
#else
  return 1.0f / r;
#endif
#else
  return 1.0f / r;
#endif
}

// ---------------------------------------------------------------------------
// Prep: pack w1 / even rows of w2 into MFMA-fragment order (bf16):
//   w1p[(nt*4+kt)*512 + l*8 + e] = w1[(nt*16 + (l&15))*128 + kt*32 + (l>>4)*8 + e]
//   w2p[kt*512 + l*8 + e]        = w2[(2*(l&15))*128   + kt*32 + (l>>4)*8 + e]
// ---------------------------------------------------------------------------
__global__ __launch_bounds__(256) void k_prep(
    const float* __restrict__ w1, const float* __restrict__ w2,
    unsigned short* __restrict__ w1p, unsigned short* __restrict__ w2p)
{
  const int t = blockIdx.x * 256 + threadIdx.x;   // 0..18431
  if (t < 16384) {
    const int e  = t & 7;
    const int l  = (t >> 3) & 63;
    const int kt = (t >> 9) & 3;
    const int nt = t >> 11;
    const int n  = nt * 16 + (l & 15);
    const int k  = kt * 32 + (l >> 4) * 8 + e;
    w1p[t] = f2bf(w1[n * 128 + k]);
  } else {
    const int u  = t - 16384;                     // 0..2047
    const int e  = u & 7;
    const int l  = (u >> 3) & 63;
    const int kt = u >> 9;
    const int n  = 2 * (l & 15);                  // even rows only
    const int k  = kt * 32 + (l >> 4) * 8 + e;
    w2p[u] = f2bf(w2[n * 128 + k]);
  }
}

// ---------------------------------------------------------------------------
// K1 (MFMA). One block per (b, y, 64-px x-tile). 256 threads = 4 waves.
// R6: EXACT R2/R3 version restored. R5's two-pass w1 at (256,4) hit the
// VGPR cap (64) and spilled (WRITE_SIZE 9.2->46MB, dur 63us); reverted.
// Lessons ledger: (256,8)->VGPR 32 spill-regress [R1]; 81920B LDS -> 1
// block/CU [R4]; (256,4)+two-pass -> VGPR 64 spill [R5]. (256,3) is the
// proven operating point: 51.7KB LDS, 3 blocks/CU, VGPR ~56, <50us.
// ---------------------------------------------------------------------------
__global__ __launch_bounds__(256, 3) void k_att(
    const float* __restrict__ x, const float* __restrict__ pbe,
    const unsigned short* __restrict__ w1p, const float* __restrict__ b1,
    const unsigned short* __restrict__ w2p, const float* __restrict__ b2,
    float* __restrict__ att)
{
  constexpr int PH = 136;   // a1_s pitch (bf16)
  constexpr int RP = 37;    // row_s pitch (f32), odd
  __shared__ __align__(16) unsigned char smem[32768 + 128 * RP * 4];
  unsigned short* w1_s  = (unsigned short*)smem;                // frag-linear
  float*          row_s = (float*)(smem + 32768);               // [128][37]
  unsigned short* a1_s  = (unsigned short*)(smem + 32768);      // [64][136]

  const int tid = threadIdx.x;
  const int xg0 = blockIdx.x * 64;
  const int y = blockIdx.y;
  const int b = blockIdx.z;

  const float ysf = y * SCL;
  const int y0 = (int)ysf;
  const int y1 = min(y0 + 1, HI - 1);
  const float wy = ysf - (float)y0;
  const int xi0 = (int)(xg0 * SCL);

  const int lane = tid & 63;
  const int wv = tid >> 6;        // wave id 0..3
  const int ln = lane & 15;
  const int qd = lane >> 4;
  const int m0 = wv * 16;

  const int xg = xg0 + m0 + ln;
  const float xsf = (float)xg * SCL;
  const int x0i = (int)xsf;
  const float wx = xsf - (float)x0i;
  const int xl = x0i - xi0;             // 0..32, xl+1 <= 33

  // ---- w1p stage loads (global->reg), issued first: 8 x float4 per thread
  float4 wstage[8];
  {
    const float4* wp4 = (const float4*)w1p;   // 2048 float4
    #pragma unroll
    for (int i = 0; i < 8; ++i) wstage[i] = wp4[tid + 256 * i];
  }

  // ---- hoisted w2 fragments (4 x 16B, L2-hot) + biases
  bf16x8 b2f[4];
  #pragma unroll
  for (int kt = 0; kt < 4; ++kt)
    b2f[kt] = *(const bf16x8*)&w2p[kt * 512 + lane * 8];
  float bias1[8];
  #pragma unroll
  for (int nt = 0; nt < 8; ++nt) bias1[nt] = b1[nt * 16 + ln];
  const float bias2 = b2[2 * ln];

  // ---- hoisted x loads: xr[kt*8+j] = x[c = kt*32+qd*8+j][y][xg]
  float xr[32];
  #pragma unroll
  for (int kt = 0; kt < 4; ++kt) {
    #pragma unroll
    for (int j = 0; j < 8; ++j) {
      const int c = kt * 32 + qd * 8 + j;
      xr[kt * 8 + j] = x[((size_t)(b * Cc + c) * Hc + y) * Wc + xg];
    }
  }

  // ---- phase 1: row_s[c][xi] = y-interp of pbe (coalesced loads, f32)
  #pragma unroll
  for (int i = 0; i < 18; ++i) {
    const int f = tid + 256 * i;        // 0..4607
    const int c = f / 36;
    const int xi = f - c * 36;
    const int xgl = min(xi0 + xi, WI - 1);
    const float* p = pbe + (size_t)(b * Cc + c) * (HI * WI);
    const float top = p[y0 * WI + xgl];
    const float bot = p[y1 * WI + xgl];
    row_s[c * RP + xi] = top + wy * (bot - top);
  }

  // ---- w1 stage: reg -> LDS (linear, conflict-free)
  {
    float4* ws4 = (float4*)w1_s;
    #pragma unroll
    for (int i = 0; i < 8; ++i) ws4[tid + 256 * i] = wstage[i];
  }
  __syncthreads();

  // ---- build A-fragments in registers from xr + row_s
  bf16x8 af[4];
  #pragma unroll
  for (int kt = 0; kt < 4; ++kt) {
    #pragma unroll
    for (int j = 0; j < 8; ++j) {
      const int c = kt * 32 + qd * 8 + j;
      const float v0 = row_s[c * RP + xl];
      const float v1 = row_s[c * RP + xl + 1];
      af[kt][j] = (short)f2bf(xr[kt * 8 + j] + v0 + wx * (v1 - v0));
    }
  }
  __syncthreads();   // row_s dead -> region reusable as a1_s

  // ---- GEMM1: C[64m][128n] = h[64m][128k] * w1[128n][128k]^T (B from LDS)
  f32x4 acc[8];
  #pragma unroll
  for (int nt = 0; nt < 8; ++nt) acc[nt] = f32x4{0.f, 0.f, 0.f, 0.f};
  #pragma unroll
  for (int nt = 0; nt < 8; ++nt) {
    #pragma unroll
    for (int kt = 0; kt < 4; ++kt) {
      const bf16x8 bf = *(const bf16x8*)&w1_s[(nt * 4 + kt) * 512 + lane * 8];
      acc[nt] = __builtin_amdgcn_mfma_f32_16x16x32_bf16(af[kt], bf, acc[nt], 0, 0, 0);
    }
  }

  // epilogue: relu(+bias) -> a1_s (bf16). Wave writes only its own 16 rows.
  #pragma unroll
  for (int nt = 0; nt < 8; ++nt) {
    const int n = nt * 16 + ln;
    const float bias = bias1[nt];
    #pragma unroll
    for (int r = 0; r < 4; ++r) {
      const int m = m0 + qd * 4 + r;
      a1_s[m * PH + n] = f2bf(fmaxf(acc[nt][r] + bias, 0.f));
    }
  }
  // no __syncthreads: each wave reads back only rows it wrote

  // ---- GEMM2: att[64m][16j] = a1[64m][128k] * w2e[16j][128k]^T
  f32x4 acc2 = f32x4{0.f, 0.f, 0.f, 0.f};
  #pragma unroll
  for (int kt = 0; kt < 4; ++kt) {
    const bf16x8 a2 = *(const bf16x8*)&a1_s[(m0 + ln) * PH + kt * 32 + qd * 8];
    acc2 = __builtin_amdgcn_mfma_f32_16x16x32_bf16(a2, b2f[kt], acc2, 0, 0, 0);
  }
  #pragma unroll
  for (int r = 0; r < 4; ++r) {
    const int opx = m0 + qd * 4 + r;
    const float v = fmaxf(acc2[r] + bias2, 0.f) + 0.001f;
    att[((size_t)((b * Hc + y) * Wc) + xg0 + opx) * NA + ln] = v;
  }
}

// ---------------------------------------------------------------------------
// K2: block = half an image row (96 px), 192 threads = 96 px x 2 bin-halves.
// R6: keep R5's split (grid 1536 fixes R3's work-starvation Occ 24%) but
// repair its regressions: (192,4) not (192,6) -> VGPR cap 128 not 85 (no
// squeeze on v[32]+am[16]); staging re-vectorized as float4 over a
// 16B-aligned 52-wide window (base 44 for hx=1; all loads in-bounds).
// Pitch 56 keeps LDS float4 writes 16B-aligned. Edge px=191 handled by
// i1 = min(xl+1, 51)  (== reference's x1 = min(x0+1, 95)).
// ---------------------------------------------------------------------------
__global__ __launch_bounds__(192, 4) void k_bins(
    const float* __restrict__ pb, const float* __restrict__ att,
    float* __restrict__ out0, float* __restrict__ out1)
{
  constexpr int PW = 56;                      // pbrow pitch (16B-aligned rows)
  __shared__ __align__(16) float smem2[NB * PW];   // 14336 B
  float* pbrow = smem2;                       // [64][56], 52 used
  float* xch   = smem2;                       // [32][96] alias after delta

  const int tid = threadIdx.x;      // 0..191
  const int y  = blockIdx.x;
  const int b  = blockIdx.y;
  const int hx = blockIdx.z;        // x-half 0/1

  const int h  = (tid >= 96) ? 1 : 0;   // bin half
  const int p  = tid - 96 * h;          // local pixel 0..95
  const int px = 96 * hx + p;           // global pixel

  const float ysf = y * SCL;
  const int y0 = (int)ysf;
  const int y1 = min(y0 + 1, HI - 1);
  const float wy = ysf - (float)y0;

  // window base: hx0 covers x=[0,51], hx1 covers x=[44,95] (both aligned,
  // both fully in-bounds). Needed xl range: hx0 [0,48], hx1 [3,51].
  const int xb = hx ? 44 : 0;

  // att for this pixel: 16 floats, contiguous — issue first (independent)
  float am[16];
  {
    const float4* ap = (const float4*)(att + ((size_t)((b * Hc + y) * Wc) + px) * NA);
    const float4 a0 = ap[0], a1 = ap[1], a2 = ap[2], a3 = ap[3];
    am[0] = a0.x;  am[1] = a0.y;  am[2] = a0.z;  am[3] = a0.w;
    am[4] = a1.x;  am[5] = a1.y;  am[6] = a1.z;  am[7] = a1.w;
    am[8] = a2.x;  am[9] = a2.y;  am[10] = a2.z; am[11] = a2.w;
    am[12] = a3.x; am[13] = a3.y; am[14] = a3.z; am[15] = a3.w;
  }

  // ---- stage y-interp pb window: 64 bins x 13 float4 groups = 832 positions
  #pragma unroll
  for (int i = 0; i < 5; ++i) {
    const int u = tid + 192 * i;          // 0..959
    if (u < 832) {
      const int k = u / 13;
      const int g = u - k * 13;           // float4 group 0..12
      const float* base = pb + (size_t)(b * NB + k) * (HI * WI);
      const float4 t4 = *(const float4*)&base[y0 * WI + xb + g * 4];
      const float4 b4 = *(const float4*)&base[y1 * WI + xb + g * 4];
      float4 r;
      r.x = t4.x + wy * (b4.x - t4.x);
      r.y = t4.y + wy * (b4.y - t4.y);
      r.z = t4.z + wy * (b4.z - t4.z);
      r.w = t4.w + wy * (b4.w - t4.w);
      *(float4*)&pbrow[k * PW + g * 4] = r;
    }
  }
  __syncthreads();

  const float xsf = px * SCL;
  const int x0 = (int)xsf;
  const float wx = xsf - (float)x0;
  const int xl = x0 - xb;               // in-window index
  const int i1 = min(xl + 1, 51);       // clamp: == min(x0+1, 95) in-window

  const size_t obase = (size_t)(b * NB) * (Hc * Wc) + (size_t)y * Wc + px;
  float v[32];                          // this thread's 32 bins (k = h*32 + i)

  // ---- delta: 4 bins in flight -> 4 independent rcp chains
  #pragma unroll
  for (int kb = 0; kb < 32; kb += 4) {
    float bc[4], dl[4];
    #pragma unroll
    for (int q = 0; q < 4; ++q) {
      const int k = h * 32 + kb + q;
      const float v0 = pbrow[k * PW + xl], v1 = pbrow[k * PW + i1];
      bc[q] = v0 + wx * (v1 - v0);
      dl[q] = 0.f;
    }
    #pragma unroll
    for (int j = 0; j < NA; ++j) {
      const float a = am[j];
      #pragma unroll
      for (int q = 0; q < 4; ++q) {
        const float d = a - bc[q];
        const float rq = fmaf(300.f * d, d, 1.f);
        dl[q] = fmaf(d, rcp_fast(rq), dl[q]);
      }
    }
    #pragma unroll
    for (int q = 0; q < 4; ++q) {
      const float bnc = fmaf(dl[q], 1.f / 16.f, bc[q]);
      out0[obase + (size_t)(h * 32 + kb + q) * (Hc * Wc)] = bnc;
      v[kb + q] = fmaf(9.999f, bnc, 0.001f);
    }
  }

  // ---- per-thread bitonic sort of 32: h0 ascending, h1 descending.
  // Polarity folded into the CE flag -> single network, no divergent branch.
  #pragma unroll
  for (int size = 2; size <= 32; size <<= 1) {
    #pragma unroll
    for (int stride = size >> 1; stride >= 1; stride >>= 1) {
      #pragma unroll
      for (int i = 0; i < 32; ++i) {
        if ((i & stride) == 0) {
          const int j = i | stride;
          const bool asc = (((i & size) == 0) != (h == 1));
          const float a = v[i], c = v[j];
          const float lo = fminf(a, c), hi = fmaxf(a, c);
          v[i] = asc ? lo : hi;
          v[j] = asc ? hi : lo;
        }
      }
    }
  }

  // ---- cross-thread stride-32 CE layer through LDS (pbrow dead)
  __syncthreads();                       // all pbrow reads done
  if (h) {
    #pragma unroll
    for (int i = 0; i < 32; ++i) xch[i * 96 + p] = v[i];
  }
  __syncthreads();
  if (!h) {
    #pragma unroll
    for (int i = 0; i < 32; ++i) {
      const float o = xch[i * 96 + p];
      const float mn = fminf(v[i], o), mx = fmaxf(v[i], o);
      v[i] = mn;
      xch[i * 96 + p] = mx;
    }
  }
  __syncthreads();
  if (h) {
    #pragma unroll
    for (int i = 0; i < 32; ++i) v[i] = xch[i * 96 + p];
  }

  // ---- each half is bitonic; 5 ascending merge layers finish the sort
  #pragma unroll
  for (int stride = 16; stride >= 1; stride >>= 1) {
    #pragma unroll
    for (int i = 0; i < 32; ++i) {
      if ((i & stride) == 0) {
        const int j = i | stride;
        const float a = v[i], c = v[j];
        v[i] = fminf(a, c);
        v[j] = fmaxf(a, c);
      }
    }
  }

  // h0 holds global ranks 0..31, h1 ranks 32..63
  #pragma unroll
  for (int i = 0; i < 32; ++i) {
    out1[obase + (size_t)(h * 32 + i) * (Hc * Wc)] =
        fminf(fmaxf(v[i], 0.001f), 10.0f);
  }
}

// ---------------------------------------------------------------------------
extern "C" void kernel_launch(void* const* d_in, const int* in_sizes, int n_in,
                              void* d_out, int out_size, void* d_ws, size_t ws_size,
                              hipStream_t stream) {
  const float* x   = (const float*)d_in[0];   // (4,128,192,192)
  const float* pb  = (const float*)d_in[1];   // (4,64,96,96)
  const float* pbe = (const float*)d_in[2];   // (4,128,96,96)
  const float* w1  = (const float*)d_in[3];   // (128,128)
  const float* b1  = (const float*)d_in[4];   // (128,)
  const float* w2  = (const float*)d_in[5];   // (32,128)
  const float* b2  = (const float*)d_in[6];   // (32,)

  float* out0 = (float*)d_out;                       // bin_new_centers
  float* out1 = out0 + (size_t)Bc * NB * Hc * Wc;    // bin_centers

  // ws layout: [w1p 32KB][w2p 4KB][pad to 64KB][att f32 9.4MB]
  unsigned short* w1p = (unsigned short*)d_ws;
  unsigned short* w2p = w1p + 16384;
  float* att = (float*)((char*)d_ws + 65536);        // [b][y][x][j]

  k_prep<<<72, 256, 0, stream>>>(w1, w2, w1p, w2p);

  dim3 g1(Wc / 64, Hc, Bc);
  k_att<<<g1, 256, 0, stream>>>(x, pbe, w1p, b1, w2p, b2, att);

  dim3 g2(Hc, Bc, 2);
  k_bins<<<g2, 192, 0, stream>>>(pb, att, out0, out1);
}